// Round 8
// baseline (467.781 us; speedup 1.0000x reference)
//
#include <hip/hip_runtime.h>
#include <hip/hip_bf16.h>
#include <stdint.h>

typedef __bf16 bf16;
typedef __attribute__((ext_vector_type(8))) __bf16 bf16x8;
typedef __attribute__((ext_vector_type(4))) float f32x4;

static constexpr int kTok = 4096;    // B*S
static constexpr int kHid = 1024;
static constexpr int kInter = 4096;

enum : int { EPI_F32 = 0, EPI_BF = 1, EPI_SILU = 2 };

// C = A(MxK) * B(NxK)^T. A is fp32 (A_BF16=false, converted on stage) or
// bf16 (A_BF16=true, e.g. the H scratch). B always fp32, converted on stage.
// bf16 MFMA (no fp32 MFMA on CDNA4), fp32 accumulate.
// 128x128 tile, BK=32, 4 waves in 2x2. m97-style structure.
template <int EPI, bool A_BF16>
__global__ void __launch_bounds__(256, 2) gemm128(
    const void* Ap, const float* B, int K, int N,
    float* outF, bf16* outB, const bf16* gIn) {
  __shared__ bf16 sA[128 * 32];
  __shared__ bf16 sB[128 * 32];
  const int t = threadIdx.x;
  const int w = t >> 6;
  const int L = t & 63;
  const long m0 = (long)blockIdx.y * 128;
  const long n0 = (long)blockIdx.x * 128;
  const int wm = (w >> 1) * 64;
  const int wn = (w & 1) * 64;

  f32x4 acc[4][4];
  const f32x4 fzero = {0.f, 0.f, 0.f, 0.f};
#pragma unroll
  for (int i = 0; i < 4; ++i)
#pragma unroll
    for (int j = 0; j < 4; ++j) acc[i][j] = fzero;

  // staging chunk c in [0,512): row = c>>2, k-offset = (c&3)*8,
  // LDS elem offset = c*8 (row-major [128][32]). Thread t does c and c+256.
  const int c0 = t, c1 = t + 256;
  const long ar0 = m0 + (c0 >> 2), ar1 = m0 + (c1 >> 2);
  const long br0 = n0 + (c0 >> 2), br1 = n0 + (c1 >> 2);
  const int ko = (c0 & 3) * 8;  // == (c1&3)*8

  const int la = L & 15;
  const int lk = (L >> 4) * 8;
  const bf16* sAr = sA + (wm + la) * 32 + lk;
  const bf16* sBr = sB + (wn + la) * 32 + lk;

  const int nk = K >> 5;
  for (int kt = 0; kt < nk; ++kt) {
    const long k0 = (long)kt << 5;
    bf16x8 av0, av1, bv0, bv1;
    if (A_BF16) {
      const bf16* A = (const bf16*)Ap;
      av0 = *(const bf16x8*)(A + ar0 * K + k0 + ko);
      av1 = *(const bf16x8*)(A + ar1 * K + k0 + ko);
    } else {
      const float* A = (const float*)Ap;
      const f32x4 x0 = *(const f32x4*)(A + ar0 * K + k0 + ko);
      const f32x4 x1 = *(const f32x4*)(A + ar0 * K + k0 + ko + 4);
      const f32x4 y0 = *(const f32x4*)(A + ar1 * K + k0 + ko);
      const f32x4 y1 = *(const f32x4*)(A + ar1 * K + k0 + ko + 4);
#pragma unroll
      for (int i = 0; i < 4; ++i) {
        av0[i] = (bf16)x0[i]; av0[4 + i] = (bf16)x1[i];
        av1[i] = (bf16)y0[i]; av1[4 + i] = (bf16)y1[i];
      }
    }
    {
      const f32x4 x0 = *(const f32x4*)(B + br0 * K + k0 + ko);
      const f32x4 x1 = *(const f32x4*)(B + br0 * K + k0 + ko + 4);
      const f32x4 y0 = *(const f32x4*)(B + br1 * K + k0 + ko);
      const f32x4 y1 = *(const f32x4*)(B + br1 * K + k0 + ko + 4);
#pragma unroll
      for (int i = 0; i < 4; ++i) {
        bv0[i] = (bf16)x0[i]; bv0[4 + i] = (bf16)x1[i];
        bv1[i] = (bf16)y0[i]; bv1[4 + i] = (bf16)y1[i];
      }
    }
    __syncthreads();  // protect previous iteration's LDS reads
    *(bf16x8*)(sA + c0 * 8) = av0;
    *(bf16x8*)(sA + c1 * 8) = av1;
    *(bf16x8*)(sB + c0 * 8) = bv0;
    *(bf16x8*)(sB + c1 * 8) = bv1;
    __syncthreads();  // tiles ready

    bf16x8 af[4], bfm[4];
#pragma unroll
    for (int i = 0; i < 4; ++i) {
      af[i] = *(const bf16x8*)(sAr + i * 16 * 32);
      bfm[i] = *(const bf16x8*)(sBr + i * 16 * 32);
    }
#pragma unroll
    for (int i = 0; i < 4; ++i)
#pragma unroll
      for (int j = 0; j < 4; ++j)
        acc[i][j] = __builtin_amdgcn_mfma_f32_16x16x32_bf16(af[i], bfm[j],
                                                            acc[i][j], 0, 0, 0);
  }

  // C/D layout: col = lane&15, row = (lane>>4)*4 + reg  [m89-verified]
  const long col0 = n0 + wn + la;
  const long row0 = m0 + wm + (L >> 4) * 4;
#pragma unroll
  for (int i = 0; i < 4; ++i) {
#pragma unroll
    for (int j = 0; j < 4; ++j) {
#pragma unroll
      for (int r = 0; r < 4; ++r) {
        const long off = (row0 + i * 16 + r) * N + col0 + j * 16;
        const float v = acc[i][j][r];
        if (EPI == EPI_F32) {
          outF[off] = v;
        } else if (EPI == EPI_BF) {
          outB[off] = (bf16)v;
        } else {  // EPI_SILU
          const float g = (float)gIn[off];
          outB[off] = (bf16)(g / (1.f + __expf(-g)) * v);
        }
      }
    }
  }
}

// One wave per token. logits = fp32 (4096 x 128) row-major (== out1 flat).
// Stable rank-sort both 64-logit halves, top-8 over the 20 dominance-feasible
// (p,q) pairs ((p+1)(q+1)<=8, dominators also precede in flat pos), softmax,
// expert dot/silu/weighted accumulate, RMW into fp32 out0.
__global__ void __launch_bounds__(256) route_expert(
    const float* logits, const float* X, const float* dE, const float* uE,
    float* out0) {
  __shared__ float s_vals[4][128];
  __shared__ int s_idx[4][128];
  const int w = threadIdx.x >> 6;
  const int L = threadIdx.x & 63;
  const int j = blockIdx.x * 4 + w;

  const int half = (j & 1) * 64;
  const int rx = j >> 1;
  const float vx = logits[(long)rx * 128 + half + L];
  const float vy = logits[(long)(2048 + rx) * 128 + half + L];

  // stable rank (ties -> lower original index first) == lax.top_k full sort
  int rkx = 0, rky = 0;
  for (int m = 0; m < 64; ++m) {
    const float mx = __shfl(vx, m);
    const float my = __shfl(vy, m);
    rkx += (mx > vx) || (mx == vx && m < L);
    rky += (my > vy) || (my == vy && m < L);
  }
  rkx &= 63;  // safety clamp: no wild LDS write even under pathology
  rky &= 63;
  s_vals[w][rkx] = vx;
  s_idx[w][rkx] = L;
  s_vals[w][64 + rky] = vy;
  s_idx[w][64 + rky] = L;
  __syncthreads();

  int p = 0, q = 0;
  const bool valid = (L < 20);
  if (L < 8)       { p = L;      q = 0; }
  else if (L < 12) { p = L - 8;  q = 1; }
  else if (L < 14) { p = L - 12; q = 2; }
  else if (L < 16) { p = L - 14; q = 3; }
  else if (L < 20) { p = 0;      q = L - 12; }
  const float kNegBig = -3.0e38f;
  float myv = valid ? (s_vals[w][p] + s_vals[w][64 + q]) : kNegBig;
  int mypos = valid ? (p * 64 + q) : 0x7fffffff;

  float topv[8];
  int tope[8];
#pragma unroll
  for (int r = 0; r < 8; ++r) {
    float bv = myv;
    int bp = mypos;
#pragma unroll
    for (int d = 32; d > 0; d >>= 1) {
      const float ov = __shfl_xor(bv, d);
      const int op = __shfl_xor(bp, d);
      if (ov > bv || (ov == bv && op < bp)) { bv = ov; bp = op; }
    }
    topv[r] = bv;
    const int pp = (bp >> 6) & 127, qq = bp & 63;
    tope[r] = (s_idx[w][pp] * 64 + s_idx[w][64 + qq]) & 4095;  // clamp
    if (mypos == bp) myv = kNegBig;
  }

  float e[8], wsum = 0.f;
#pragma unroll
  for (int r = 0; r < 8; ++r) {
    e[r] = __expf(topv[r] - topv[0]);
    wsum += e[r];
  }
  const float winv = 1.f / wsum;

  // lane owns h in [L*16, L*16+16)
  const long xoff = (long)j * kHid + L * 16;
  float xv[16], acc[16];
#pragma unroll
  for (int v4 = 0; v4 < 4; ++v4) {
    const f32x4 xl = *(const f32x4*)(X + xoff + v4 * 4);
#pragma unroll
    for (int i = 0; i < 4; ++i) { xv[v4 * 4 + i] = xl[i]; acc[v4 * 4 + i] = 0.f; }
  }

  for (int r = 0; r < 8; ++r) {
    const long eo = (long)tope[r] * kHid + L * 16;
    float d = 0.f;
#pragma unroll
    for (int v4 = 0; v4 < 4; ++v4) {
      const f32x4 dl = *(const f32x4*)(dE + eo + v4 * 4);
#pragma unroll
      for (int i = 0; i < 4; ++i) d += dl[i] * xv[v4 * 4 + i];
    }
#pragma unroll
    for (int dd = 32; dd > 0; dd >>= 1) d += __shfl_xor(d, dd);
    const float ew = d / (1.f + __expf(-d)) * (e[r] * winv);
#pragma unroll
    for (int v4 = 0; v4 < 4; ++v4) {
      const f32x4 ul = *(const f32x4*)(uE + eo + v4 * 4);
#pragma unroll
      for (int i = 0; i < 4; ++i) acc[v4 * 4 + i] += ew * ul[i];
    }
  }

  float* po = out0 + xoff;
#pragma unroll
  for (int v4 = 0; v4 < 4; ++v4) {
    f32x4 ov = *(const f32x4*)(po + v4 * 4);
#pragma unroll
    for (int i = 0; i < 4; ++i) ov[i] += acc[v4 * 4 + i];
    *(f32x4*)(po + v4 * 4) = ov;
  }
}

extern "C" void kernel_launch(void* const* d_in, const int* in_sizes, int n_in,
                              void* d_out, int out_size, void* d_ws,
                              size_t ws_size, hipStream_t stream) {
  (void)in_sizes; (void)n_in; (void)out_size; (void)ws_size;
  // All fp32, per the reference dtypes (rounds 1-7 post-mortem: bf16-cast
  // reads produced NaN logits -> uninitialized-LDS expert ids -> wild gather
  // -> the SIGABRTs).
  const float* X  = (const float*)d_in[0];
  const float* Wg = (const float*)d_in[1];
  const float* Wu = (const float*)d_in[2];
  const float* Wd = (const float*)d_in[3];
  const float* Wr = (const float*)d_in[4];
  const float* dE = (const float*)d_in[5];
  const float* uE = (const float*)d_in[6];

  float* out0 = (float*)d_out;                  // (4096,1024) final
  float* out1 = out0 + (size_t)kTok * kHid;     // (2,4096,64) router logits
  bf16* wsH = (bf16*)d_ws;                      // 32 MiB gate -> H (bf16)

  dim3 blk(256);
  // router logits -> out1 (fp32); route_expert reads them from there
  gemm128<EPI_F32, false><<<dim3(1, 32), blk, 0, stream>>>(
      X, Wr, kHid, 128, out1, nullptr, nullptr);
  // gate = X*Wg^T -> wsH (bf16)
  gemm128<EPI_BF, false><<<dim3(32, 32), blk, 0, stream>>>(
      X, Wg, kHid, kInter, nullptr, wsH, nullptr);
  // H = silu(gate) * (X*Wu^T), in place over wsH
  gemm128<EPI_SILU, false><<<dim3(32, 32), blk, 0, stream>>>(
      X, Wu, kHid, kInter, nullptr, wsH, wsH);
  // mlp = H*Wd^T -> out0 (fp32)
  gemm128<EPI_F32, true><<<dim3(8, 32), blk, 0, stream>>>(
      wsH, Wd, kInter, kHid, out0, nullptr, nullptr);
  // routing + experts, RMW out0
  route_expert<<<dim3(kTok / 4), blk, 0, stream>>>(out1, X, dE, uE, out0);
}

// Round 9
// 410.763 us; speedup vs baseline: 1.1388x; 1.1388x over previous
//
#include <hip/hip_runtime.h>
#include <hip/hip_bf16.h>
#include <stdint.h>

typedef __bf16 bf16;
typedef __attribute__((ext_vector_type(8))) __bf16 bf16x8;
typedef __attribute__((ext_vector_type(4))) float f32x4;

static constexpr int kTok = 4096;    // B*S
static constexpr int kHid = 1024;
static constexpr int kInter = 4096;

// ---------------- router GEMM (fp32 A/B staged->bf16 MFMA) ----------------
// C(4096x128) = X(4096x1024) * Wr(128x1024)^T, fp32 out. 128x128 tile, BK=32.
__global__ void __launch_bounds__(256, 2) gemm_router(
    const float* A, const float* B, float* outF) {
  constexpr int K = kHid, N = 128;
  __shared__ bf16 sA[128 * 32];
  __shared__ bf16 sB[128 * 32];
  const int t = threadIdx.x;
  const int w = t >> 6;
  const int L = t & 63;
  const long m0 = (long)blockIdx.y * 128;
  const int wm = (w >> 1) * 64;
  const int wn = (w & 1) * 64;

  f32x4 acc[4][4];
  const f32x4 fzero = {0.f, 0.f, 0.f, 0.f};
#pragma unroll
  for (int i = 0; i < 4; ++i)
#pragma unroll
    for (int j = 0; j < 4; ++j) acc[i][j] = fzero;

  const int c0 = t, c1 = t + 256;
  const long ar0 = m0 + (c0 >> 2), ar1 = m0 + (c1 >> 2);
  const long br0 = (c0 >> 2), br1 = (c1 >> 2);
  const int ko = (c0 & 3) * 8;

  const int la = L & 15;
  const int lk = (L >> 4) * 8;
  const bf16* sAr = sA + (wm + la) * 32 + lk;
  const bf16* sBr = sB + (wn + la) * 32 + lk;

  for (int kt = 0; kt < K / 32; ++kt) {
    const long k0 = (long)kt << 5;
    bf16x8 av0, av1, bv0, bv1;
    {
      const f32x4 x0 = *(const f32x4*)(A + ar0 * K + k0 + ko);
      const f32x4 x1 = *(const f32x4*)(A + ar0 * K + k0 + ko + 4);
      const f32x4 y0 = *(const f32x4*)(A + ar1 * K + k0 + ko);
      const f32x4 y1 = *(const f32x4*)(A + ar1 * K + k0 + ko + 4);
      const f32x4 p0 = *(const f32x4*)(B + br0 * K + k0 + ko);
      const f32x4 p1 = *(const f32x4*)(B + br0 * K + k0 + ko + 4);
      const f32x4 q0 = *(const f32x4*)(B + br1 * K + k0 + ko);
      const f32x4 q1 = *(const f32x4*)(B + br1 * K + k0 + ko + 4);
#pragma unroll
      for (int i = 0; i < 4; ++i) {
        av0[i] = (bf16)x0[i]; av0[4 + i] = (bf16)x1[i];
        av1[i] = (bf16)y0[i]; av1[4 + i] = (bf16)y1[i];
        bv0[i] = (bf16)p0[i]; bv0[4 + i] = (bf16)p1[i];
        bv1[i] = (bf16)q0[i]; bv1[4 + i] = (bf16)q1[i];
      }
    }
    __syncthreads();
    *(bf16x8*)(sA + c0 * 8) = av0;
    *(bf16x8*)(sA + c1 * 8) = av1;
    *(bf16x8*)(sB + c0 * 8) = bv0;
    *(bf16x8*)(sB + c1 * 8) = bv1;
    __syncthreads();
    bf16x8 af[4], bfm[4];
#pragma unroll
    for (int i = 0; i < 4; ++i) {
      af[i] = *(const bf16x8*)(sAr + i * 16 * 32);
      bfm[i] = *(const bf16x8*)(sBr + i * 16 * 32);
    }
#pragma unroll
    for (int i = 0; i < 4; ++i)
#pragma unroll
      for (int j = 0; j < 4; ++j)
        acc[i][j] = __builtin_amdgcn_mfma_f32_16x16x32_bf16(af[i], bfm[j],
                                                            acc[i][j], 0, 0, 0);
  }
  const long col0 = wn + la;
  const long row0 = m0 + wm + (L >> 4) * 4;
#pragma unroll
  for (int i = 0; i < 4; ++i)
#pragma unroll
    for (int j = 0; j < 4; ++j)
#pragma unroll
      for (int r = 0; r < 4; ++r)
        outF[(row0 + i * 16 + r) * N + col0 + j * 16] = acc[i][j][r];
}

// ---------------- fused gate+up+silu ----------------
// H(4096x4096) = silu(X*Wg^T) * (X*Wu^T), bf16 out to ws.
// Stages X once per K-step, two accumulator sets (32 MFMA / staged X-tile).
__global__ void __launch_bounds__(256, 2) gemm_gu(
    const float* X, const float* Wg, const float* Wu, bf16* H) {
  constexpr int K = kHid, N = kInter;
  __shared__ bf16 sX[128 * 32];
  __shared__ bf16 sG[128 * 32];
  __shared__ bf16 sU[128 * 32];
  const int t = threadIdx.x;
  const int w = t >> 6;
  const int L = t & 63;
  const long m0 = (long)blockIdx.y * 128;
  const long n0 = (long)blockIdx.x * 128;
  const int wm = (w >> 1) * 64;
  const int wn = (w & 1) * 64;

  f32x4 accG[4][4], accU[4][4];
  const f32x4 fzero = {0.f, 0.f, 0.f, 0.f};
#pragma unroll
  for (int i = 0; i < 4; ++i)
#pragma unroll
    for (int j = 0; j < 4; ++j) { accG[i][j] = fzero; accU[i][j] = fzero; }

  const int c0 = t, c1 = t + 256;
  const long xr0 = m0 + (c0 >> 2), xr1 = m0 + (c1 >> 2);
  const long wr0 = n0 + (c0 >> 2), wr1 = n0 + (c1 >> 2);
  const int ko = (c0 & 3) * 8;

  const int la = L & 15;
  const int lk = (L >> 4) * 8;
  const bf16* sXr = sX + (wm + la) * 32 + lk;
  const bf16* sGr = sG + (wn + la) * 32 + lk;
  const bf16* sUr = sU + (wn + la) * 32 + lk;

  for (int kt = 0; kt < K / 32; ++kt) {
    const long k0 = (long)kt << 5;
    bf16x8 xv0, xv1, gv0, gv1, uv0, uv1;
    {
      const f32x4 a0 = *(const f32x4*)(X + xr0 * K + k0 + ko);
      const f32x4 a1 = *(const f32x4*)(X + xr0 * K + k0 + ko + 4);
      const f32x4 b0 = *(const f32x4*)(X + xr1 * K + k0 + ko);
      const f32x4 b1 = *(const f32x4*)(X + xr1 * K + k0 + ko + 4);
      const f32x4 g0 = *(const f32x4*)(Wg + wr0 * K + k0 + ko);
      const f32x4 g1 = *(const f32x4*)(Wg + wr0 * K + k0 + ko + 4);
      const f32x4 h0 = *(const f32x4*)(Wg + wr1 * K + k0 + ko);
      const f32x4 h1 = *(const f32x4*)(Wg + wr1 * K + k0 + ko + 4);
      const f32x4 u0 = *(const f32x4*)(Wu + wr0 * K + k0 + ko);
      const f32x4 u1 = *(const f32x4*)(Wu + wr0 * K + k0 + ko + 4);
      const f32x4 v0 = *(const f32x4*)(Wu + wr1 * K + k0 + ko);
      const f32x4 v1 = *(const f32x4*)(Wu + wr1 * K + k0 + ko + 4);
#pragma unroll
      for (int i = 0; i < 4; ++i) {
        xv0[i] = (bf16)a0[i]; xv0[4 + i] = (bf16)a1[i];
        xv1[i] = (bf16)b0[i]; xv1[4 + i] = (bf16)b1[i];
        gv0[i] = (bf16)g0[i]; gv0[4 + i] = (bf16)g1[i];
        gv1[i] = (bf16)h0[i]; gv1[4 + i] = (bf16)h1[i];
        uv0[i] = (bf16)u0[i]; uv0[4 + i] = (bf16)u1[i];
        uv1[i] = (bf16)v0[i]; uv1[4 + i] = (bf16)v1[i];
      }
    }
    __syncthreads();
    *(bf16x8*)(sX + c0 * 8) = xv0;
    *(bf16x8*)(sX + c1 * 8) = xv1;
    *(bf16x8*)(sG + c0 * 8) = gv0;
    *(bf16x8*)(sG + c1 * 8) = gv1;
    *(bf16x8*)(sU + c0 * 8) = uv0;
    *(bf16x8*)(sU + c1 * 8) = uv1;
    __syncthreads();
    bf16x8 af[4], bg[4], bu[4];
#pragma unroll
    for (int i = 0; i < 4; ++i) {
      af[i] = *(const bf16x8*)(sXr + i * 16 * 32);
      bg[i] = *(const bf16x8*)(sGr + i * 16 * 32);
      bu[i] = *(const bf16x8*)(sUr + i * 16 * 32);
    }
#pragma unroll
    for (int i = 0; i < 4; ++i)
#pragma unroll
      for (int j = 0; j < 4; ++j) {
        accG[i][j] = __builtin_amdgcn_mfma_f32_16x16x32_bf16(af[i], bg[j],
                                                             accG[i][j], 0, 0, 0);
        accU[i][j] = __builtin_amdgcn_mfma_f32_16x16x32_bf16(af[i], bu[j],
                                                             accU[i][j], 0, 0, 0);
      }
  }
  const long col0 = n0 + wn + la;
  const long row0 = m0 + wm + (L >> 4) * 4;
#pragma unroll
  for (int i = 0; i < 4; ++i)
#pragma unroll
    for (int j = 0; j < 4; ++j)
#pragma unroll
      for (int r = 0; r < 4; ++r) {
        const float g = accG[i][j][r];
        const float u = accU[i][j][r];
        H[(row0 + i * 16 + r) * N + col0 + j * 16] =
            (bf16)(g / (1.f + __expf(-g)) * u);
      }
}

// ---------------- down GEMM, split-K=2, atomic accumulate ----------------
// out0(4096x1024) += H(4096x4096,bf16) * Wd(1024x4096)^T over K-half z.
__global__ void __launch_bounds__(256, 2) gemm_down(
    const bf16* Hs, const float* B, float* out0) {
  constexpr int K = kInter, N = kHid;
  __shared__ bf16 sA[128 * 32];
  __shared__ bf16 sB[128 * 32];
  const int t = threadIdx.x;
  const int w = t >> 6;
  const int L = t & 63;
  const long m0 = (long)blockIdx.y * 128;
  const long n0 = (long)blockIdx.x * 128;
  const long zb = (long)blockIdx.z * 2048;  // K-half base
  const int wm = (w >> 1) * 64;
  const int wn = (w & 1) * 64;

  f32x4 acc[4][4];
  const f32x4 fzero = {0.f, 0.f, 0.f, 0.f};
#pragma unroll
  for (int i = 0; i < 4; ++i)
#pragma unroll
    for (int j = 0; j < 4; ++j) acc[i][j] = fzero;

  const int c0 = t, c1 = t + 256;
  const long ar0 = m0 + (c0 >> 2), ar1 = m0 + (c1 >> 2);
  const long br0 = n0 + (c0 >> 2), br1 = n0 + (c1 >> 2);
  const int ko = (c0 & 3) * 8;

  const int la = L & 15;
  const int lk = (L >> 4) * 8;
  const bf16* sAr = sA + (wm + la) * 32 + lk;
  const bf16* sBr = sB + (wn + la) * 32 + lk;

  for (int kt = 0; kt < 64; ++kt) {
    const long k0 = zb + ((long)kt << 5);
    const bf16x8 av0 = *(const bf16x8*)(Hs + ar0 * K + k0 + ko);
    const bf16x8 av1 = *(const bf16x8*)(Hs + ar1 * K + k0 + ko);
    bf16x8 bv0, bv1;
    {
      const f32x4 p0 = *(const f32x4*)(B + br0 * K + k0 + ko);
      const f32x4 p1 = *(const f32x4*)(B + br0 * K + k0 + ko + 4);
      const f32x4 q0 = *(const f32x4*)(B + br1 * K + k0 + ko);
      const f32x4 q1 = *(const f32x4*)(B + br1 * K + k0 + ko + 4);
#pragma unroll
      for (int i = 0; i < 4; ++i) {
        bv0[i] = (bf16)p0[i]; bv0[4 + i] = (bf16)p1[i];
        bv1[i] = (bf16)q0[i]; bv1[4 + i] = (bf16)q1[i];
      }
    }
    __syncthreads();
    *(bf16x8*)(sA + c0 * 8) = av0;
    *(bf16x8*)(sA + c1 * 8) = av1;
    *(bf16x8*)(sB + c0 * 8) = bv0;
    *(bf16x8*)(sB + c1 * 8) = bv1;
    __syncthreads();
    bf16x8 af[4], bfm[4];
#pragma unroll
    for (int i = 0; i < 4; ++i) {
      af[i] = *(const bf16x8*)(sAr + i * 16 * 32);
      bfm[i] = *(const bf16x8*)(sBr + i * 16 * 32);
    }
#pragma unroll
    for (int i = 0; i < 4; ++i)
#pragma unroll
      for (int j = 0; j < 4; ++j)
        acc[i][j] = __builtin_amdgcn_mfma_f32_16x16x32_bf16(af[i], bfm[j],
                                                            acc[i][j], 0, 0, 0);
  }
  const long col0 = n0 + wn + la;
  const long row0 = m0 + wm + (L >> 4) * 4;
#pragma unroll
  for (int i = 0; i < 4; ++i)
#pragma unroll
    for (int j = 0; j < 4; ++j)
#pragma unroll
      for (int r = 0; r < 4; ++r)
        __hip_atomic_fetch_add(
            &out0[(row0 + i * 16 + r) * N + col0 + j * 16], acc[i][j][r],
            __ATOMIC_RELAXED, __HIP_MEMORY_SCOPE_AGENT);
}

__global__ void k_zero4(float* p) {
  const long i = ((long)blockIdx.x * 256 + threadIdx.x) * 4;
  const f32x4 z = {0.f, 0.f, 0.f, 0.f};
  *(f32x4*)(p + i) = z;
}

// ---------------- routing + experts (unchanged from round 8) ----------------
__global__ void __launch_bounds__(256) route_expert(
    const float* logits, const float* X, const float* dE, const float* uE,
    float* out0) {
  __shared__ float s_vals[4][128];
  __shared__ int s_idx[4][128];
  const int w = threadIdx.x >> 6;
  const int L = threadIdx.x & 63;
  const int j = blockIdx.x * 4 + w;

  const int half = (j & 1) * 64;
  const int rx = j >> 1;
  const float vx = logits[(long)rx * 128 + half + L];
  const float vy = logits[(long)(2048 + rx) * 128 + half + L];

  int rkx = 0, rky = 0;
  for (int m = 0; m < 64; ++m) {
    const float mx = __shfl(vx, m);
    const float my = __shfl(vy, m);
    rkx += (mx > vx) || (mx == vx && m < L);
    rky += (my > vy) || (my == vy && m < L);
  }
  rkx &= 63;
  rky &= 63;
  s_vals[w][rkx] = vx;
  s_idx[w][rkx] = L;
  s_vals[w][64 + rky] = vy;
  s_idx[w][64 + rky] = L;
  __syncthreads();

  int p = 0, q = 0;
  const bool valid = (L < 20);
  if (L < 8)       { p = L;      q = 0; }
  else if (L < 12) { p = L - 8;  q = 1; }
  else if (L < 14) { p = L - 12; q = 2; }
  else if (L < 16) { p = L - 14; q = 3; }
  else if (L < 20) { p = 0;      q = L - 12; }
  const float kNegBig = -3.0e38f;
  float myv = valid ? (s_vals[w][p] + s_vals[w][64 + q]) : kNegBig;
  int mypos = valid ? (p * 64 + q) : 0x7fffffff;

  float topv[8];
  int tope[8];
#pragma unroll
  for (int r = 0; r < 8; ++r) {
    float bv = myv;
    int bp = mypos;
#pragma unroll
    for (int d = 32; d > 0; d >>= 1) {
      const float ov = __shfl_xor(bv, d);
      const int op = __shfl_xor(bp, d);
      if (ov > bv || (ov == bv && op < bp)) { bv = ov; bp = op; }
    }
    topv[r] = bv;
    const int pp = (bp >> 6) & 127, qq = bp & 63;
    tope[r] = (s_idx[w][pp] * 64 + s_idx[w][64 + qq]) & 4095;
    if (mypos == bp) myv = kNegBig;
  }

  float e[8], wsum = 0.f;
#pragma unroll
  for (int r = 0; r < 8; ++r) {
    e[r] = __expf(topv[r] - topv[0]);
    wsum += e[r];
  }
  const float winv = 1.f / wsum;

  const long xoff = (long)j * kHid + L * 16;
  float xv[16], acc[16];
#pragma unroll
  for (int v4 = 0; v4 < 4; ++v4) {
    const f32x4 xl = *(const f32x4*)(X + xoff + v4 * 4);
#pragma unroll
    for (int i = 0; i < 4; ++i) { xv[v4 * 4 + i] = xl[i]; acc[v4 * 4 + i] = 0.f; }
  }

  for (int r = 0; r < 8; ++r) {
    const long eo = (long)tope[r] * kHid + L * 16;
    float d = 0.f;
#pragma unroll
    for (int v4 = 0; v4 < 4; ++v4) {
      const f32x4 dl = *(const f32x4*)(dE + eo + v4 * 4);
#pragma unroll
      for (int i = 0; i < 4; ++i) d += dl[i] * xv[v4 * 4 + i];
    }
#pragma unroll
    for (int dd = 32; dd > 0; dd >>= 1) d += __shfl_xor(d, dd);
    const float ew = d / (1.f + __expf(-d)) * (e[r] * winv);
#pragma unroll
    for (int v4 = 0; v4 < 4; ++v4) {
      const f32x4 ul = *(const f32x4*)(uE + eo + v4 * 4);
#pragma unroll
      for (int i = 0; i < 4; ++i) acc[v4 * 4 + i] += ew * ul[i];
    }
  }

  float* po = out0 + xoff;
#pragma unroll
  for (int v4 = 0; v4 < 4; ++v4) {
    f32x4 ov = *(const f32x4*)(po + v4 * 4);
#pragma unroll
    for (int i = 0; i < 4; ++i) ov[i] += acc[v4 * 4 + i];
    *(f32x4*)(po + v4 * 4) = ov;
  }
}

extern "C" void kernel_launch(void* const* d_in, const int* in_sizes, int n_in,
                              void* d_out, int out_size, void* d_ws,
                              size_t ws_size, hipStream_t stream) {
  (void)in_sizes; (void)n_in; (void)out_size; (void)ws_size;
  const float* X  = (const float*)d_in[0];
  const float* Wg = (const float*)d_in[1];
  const float* Wu = (const float*)d_in[2];
  const float* Wd = (const float*)d_in[3];
  const float* Wr = (const float*)d_in[4];
  const float* dE = (const float*)d_in[5];
  const float* uE = (const float*)d_in[6];

  float* out0 = (float*)d_out;                  // (4096,1024) final
  float* out1 = out0 + (size_t)kTok * kHid;     // (2,4096,64) router logits
  bf16* wsH = (bf16*)d_ws;                      // 32 MiB H (bf16)

  dim3 blk(256);
  // zero out0 (atomic split-K accumulates into it)
  k_zero4<<<dim3(kTok * kHid / 1024), blk, 0, stream>>>(out0);
  // router logits -> out1 (fp32); route_expert reads them from there
  gemm_router<<<dim3(1, 32), blk, 0, stream>>>(X, Wr, out1);
  // H = silu(X*Wg^T) * (X*Wu^T) -> wsH, fused
  gemm_gu<<<dim3(32, 32), blk, 0, stream>>>(X, Wg, Wu, wsH);
  // out0 += H*Wd^T, split-K=2 (512 blocks, 2/CU)
  gemm_down<<<dim3(8, 32, 2), blk, 0, stream>>>(wsH, Wd, out0);
  // routing + experts, RMW out0
  route_expert<<<dim3(kTok / 4), blk, 0, stream>>>(out1, X, dE, uE, out0);
}